// Round 3
// baseline (32397.629 us; speedup 1.0000x reference)
//
#include <hip/hip_runtime.h>
#include <hip/hip_bf16.h>

// ---------------------------------------------------------------------------
// 2-layer LSTM, B=32, T=512, H=1024, fp32 in/out.
// Round 3: partial hi/lo bf16 split. fp32-accurate input-projection terms
//   (x@w_ih0, y0@w_ih1: both operand sides lo-corrected) + h-storage lo for
//   recurrent terms. w_hh kept hi-only (smallest error class) to cut
//   persistent weight registers 256->192. Every inline-asm MFMA carries an
//   internal s_nop 2 guard so compiler-inserted VALU writes (spill reloads,
//   v_mov) before the MFMA cannot violate wait-state hazards.
//   persistent kernel: 256 wgs (1/CU) x 256 thr (4 waves), step s computes
//   L0 t=s and L1 t=s-1, grid barrier via global counter.
// ---------------------------------------------------------------------------

constexpr int Hh = 1024;
constexpr int Bb = 32;
constexpr int Tt = 512;
constexpr int NWG = 256;

typedef float f32x4 __attribute__((ext_vector_type(4)));
typedef int   i32x4 __attribute__((ext_vector_type(4)));

__device__ inline void mfma_bf16(f32x4& acc, i32x4 a, i32x4 b) {
    // s_nop 2 inside the asm: guards VALU-write -> MFMA-read (srcA/B/C)
    // hazards from compiler-scheduled code the asm can't see.
    asm("s_nop 2\n\tv_mfma_f32_16x16x32_bf16 %0, %1, %2, %0"
        : "+v"(acc) : "v"(a), "v"(b));
}

__device__ inline unsigned short f2bf(float f) {
    unsigned u = __float_as_uint(f);
    u += 0x7fffu + ((u >> 16) & 1u);   // round-to-nearest-even
    return (unsigned short)(u >> 16);
}
__device__ inline float bf2f(unsigned short s) {
    return __uint_as_float((unsigned)s << 16);
}

__device__ inline float sigm(float x)  { return 1.f / (1.f + __expf(-x)); }
__device__ inline float tanh_f(float x){ return 1.f - 2.f / (__expf(2.f * x) + 1.f); }

// x [32][512][1024] f32 -> xT hi/lo [513][32][1024] bf16 (slot 512 zeroed)
__global__ __launch_bounds__(256) void k_xT(const float* __restrict__ x,
                                            unsigned short* __restrict__ xh,
                                            unsigned short* __restrict__ xl,
                                            int use_lo) {
    int bid = blockIdx.x;               // 0..16415
    int t = bid >> 5, b = bid & 31;
    size_t o = ((size_t)t * Bb + b) * Hh;
    if (t == Tt) {                      // dummy slot read at s==Tt: make it 0
        ushort4 z = {0, 0, 0, 0};
        ((ushort4*)(xh + o))[threadIdx.x] = z;
        if (use_lo) ((ushort4*)(xl + o))[threadIdx.x] = z;
        return;
    }
    const float4* src = (const float4*)(x + ((size_t)b * Tt + t) * Hh);
    float4 v = src[threadIdx.x];
    ushort4 hi;
    hi.x = f2bf(v.x); hi.y = f2bf(v.y); hi.z = f2bf(v.z); hi.w = f2bf(v.w);
    ((ushort4*)(xh + o))[threadIdx.x] = hi;
    if (use_lo) {
        ushort4 lo;
        lo.x = f2bf(v.x - bf2f(hi.x));
        lo.y = f2bf(v.y - bf2f(hi.y));
        lo.z = f2bf(v.z - bf2f(hi.z));
        lo.w = f2bf(v.w - bf2f(hi.w));
        ((ushort4*)(xl + o))[threadIdx.x] = lo;
    }
}

// W[mat] [1024][4096] f32 -> wh[mat][wg][col(16)][k(1024)] bf16 (4 mats),
// lo planes only for mats 0,2 (w_ih0, w_ih1) packed at lo-slot mat>>1.
__global__ __launch_bounds__(256) void k_warr(const float* __restrict__ w0,
                                              const float* __restrict__ w1,
                                              const float* __restrict__ w2,
                                              const float* __restrict__ w3,
                                              unsigned short* __restrict__ wh,
                                              unsigned short* __restrict__ wl,
                                              int use_lo) {
    int bid = blockIdx.x;               // 0..1023
    int mat = bid >> 8, wg = bid & 255;
    const float* W = (mat == 0) ? w0 : (mat == 1) ? w1 : (mat == 2) ? w2 : w3;
    size_t dbase = ((size_t)(mat * NWG + wg) * 16) * Hh;
    size_t dlo   = ((size_t)(((mat >> 1) & 1) * NWG + wg) * 16) * Hh;
    const bool want_lo = use_lo && ((mat & 1) == 0);
    for (int it = 0; it < 64; ++it) {
        int idx = it * 256 + (int)threadIdx.x;
        int col = idx >> 10, k = idx & 1023;
        int cg = (col >> 2) * Hh + wg * 4 + (col & 3);
        float w = W[(size_t)k * 4096 + cg];
        unsigned short hi = f2bf(w);
        wh[dbase + (size_t)col * Hh + k] = hi;
        if (want_lo) wl[dlo + (size_t)col * Hh + k] = f2bf(w - bf2f(hi));
    }
}

template <bool USE_LO>
__global__ __launch_bounds__(256, 1) void k_lstm(
    const unsigned short* __restrict__ xTh,
    const unsigned short* __restrict__ xTl,
    const unsigned short* __restrict__ warrh,
    const unsigned short* __restrict__ warrl,
    unsigned short* __restrict__ h0h, unsigned short* __restrict__ h0l,
    unsigned short* __restrict__ h1h, unsigned short* __restrict__ h1l,
    unsigned int*   __restrict__ counter,
    const float* __restrict__ b0,
    const float* __restrict__ b1,
    float* __restrict__ out)
{
    __shared__ float red[2][4][32][17];     // [layer][wave][batch(row)][col(+pad)]

    const int tid  = threadIdx.x;
    const int wave = tid >> 6;
    const int l    = tid & 63;
    const int wg   = blockIdx.x;

    // ---- persistent B fragments (weights) in registers ----
    // hi: all 4 mats (128 VGPR). lo: w_ih0, w_ih1 only (64 VGPR).
    i32x4 Bih0h[8], Bhh0h[8], Bih1h[8], Bhh1h[8];
    i32x4 Bih0l[8], Bih1l[8];
    {
        const size_t matStride = (size_t)NWG * 16 * Hh;
        const size_t wgOff = (size_t)wg * 16 * Hh;
        const int laneOff = (l & 15) * Hh + ((l >> 4) * 8);
        #pragma unroll
        for (int kk = 0; kk < 8; ++kk) {
            int off = laneOff + wave * 256 + kk * 32;
            Bih0h[kk] = *(const i32x4*)(warrh + 0 * matStride + wgOff + off);
            Bhh0h[kk] = *(const i32x4*)(warrh + 1 * matStride + wgOff + off);
            Bih1h[kk] = *(const i32x4*)(warrh + 2 * matStride + wgOff + off);
            Bhh1h[kk] = *(const i32x4*)(warrh + 3 * matStride + wgOff + off);
            if (USE_LO) {
                Bih0l[kk] = *(const i32x4*)(warrl + 0 * matStride + wgOff + off);
                Bih1l[kk] = *(const i32x4*)(warrl + 1 * matStride + wgOff + off);
            }
        }
    }

    // ---- epilogue cell ownership: tid<128 -> layer0, tid>=128 -> layer1 ----
    const int cid = tid & 127;
    const int cb  = cid & 31;          // batch
    const int ca  = (cid >> 5) & 3;    // local unit
    const int cu  = wg * 4 + ca;       // global hidden unit
    const float* bias = (tid < 128) ? b0 : b1;
    const float bi  = bias[cu];
    const float bf_ = bias[Hh + cu];
    const float bg  = bias[2 * Hh + cu];
    const float bo  = bias[3 * Hh + cu];
    float c = 0.f;

    const int laneA = (l & 15) * Hh + ((l >> 4) * 8);

    for (int s = 0; s <= Tt; ++s) {
        const int par_w = s & 1;
        const int par_r = par_w ^ 1;
        const size_t stepOff = (size_t)s * (Bb * Hh);
        const size_t parROff = (size_t)par_r * (Bb * Hh);
        const size_t parWOff = (size_t)par_w * (Bb * Hh);
        const unsigned short* xph  = xTh + stepOff;
        const unsigned short* xpl  = xTl + stepOff;
        const unsigned short* h0rh = h0h + parROff;
        const unsigned short* h0rl = h0l + parROff;
        const unsigned short* h1rh = h1h + parWOff;
        const unsigned short* h1rl = h1l + parWOff;

        f32x4 a00 = {0,0,0,0}, a01 = {0,0,0,0}, a10 = {0,0,0,0}, a11 = {0,0,0,0};

        #pragma unroll
        for (int m = 0; m < 2; ++m) {
            f32x4& acc0 = m ? a01 : a00;
            f32x4& acc1 = m ? a11 : a10;
            #pragma unroll
            for (int kk = 0; kk < 8; ++kk) {
                const int off = laneA + m * 16 * Hh + wave * 256 + kk * 32;
                i32x4 axh = *(const i32x4*)(xph  + off);
                i32x4 g0h = *(const i32x4*)(h0rh + off);
                i32x4 g1h = *(const i32x4*)(h1rh + off);
                // L0 hi: x@Wih0 + h0@Whh0 ; L1 hi: y0@Wih1 + h1@Whh1
                mfma_bf16(acc0, axh, Bih0h[kk]);
                mfma_bf16(acc0, g0h, Bhh0h[kk]);
                mfma_bf16(acc1, g0h, Bih1h[kk]);
                mfma_bf16(acc1, g1h, Bhh1h[kk]);
                if (USE_LO) {
                    i32x4 axl = *(const i32x4*)(xpl  + off);
                    i32x4 g0l = *(const i32x4*)(h0rl + off);
                    i32x4 g1l = *(const i32x4*)(h1rl + off);
                    mfma_bf16(acc0, axh, Bih0l[kk]);   // x * dWih0
                    mfma_bf16(acc0, axl, Bih0h[kk]);   // dx * Wih0
                    mfma_bf16(acc0, g0l, Bhh0h[kk]);   // dh0 * Whh0
                    mfma_bf16(acc1, g0h, Bih1l[kk]);   // y0 * dWih1
                    mfma_bf16(acc1, g0l, Bih1h[kk]);   // dy0 * Wih1
                    mfma_bf16(acc1, g1l, Bhh1h[kk]);   // dh1 * Whh1
                }
            }
        }
        asm("s_nop 7\n\ts_nop 7" : "+v"(a00), "+v"(a01), "+v"(a10), "+v"(a11)); // MFMA->VALU hazard

        {
            const int r0 = (l >> 4) * 4;   // C/D: col=lane&15, row=(lane>>4)*4+reg [m89]
            const int cc = l & 15;
            #pragma unroll
            for (int r = 0; r < 4; ++r) {
                red[0][wave][r0 + r][cc]      = a00[r];
                red[0][wave][16 + r0 + r][cc] = a01[r];
                red[1][wave][r0 + r][cc]      = a10[r];
                red[1][wave][16 + r0 + r][cc] = a11[r];
            }
        }
        __syncthreads();

        if (tid < 128) {                    // ---- layer 0 epilogue, t = s ----
            if (s < Tt) {
                float vi = bi, vf = bf_, vg = bg, vo = bo;
                #pragma unroll
                for (int w = 0; w < 4; ++w) {
                    vi += red[0][w][cb][ca];
                    vf += red[0][w][cb][4 + ca];
                    vg += red[0][w][cb][8 + ca];
                    vo += red[0][w][cb][12 + ca];
                }
                float ig = sigm(vi), fg = sigm(vf), gg = tanh_f(vg), og = sigm(vo);
                c = fg * c + ig * gg;
                float h = og * tanh_f(c);
                size_t idx = parWOff + (size_t)cb * Hh + cu;
                unsigned short hh = f2bf(h);
                h0h[idx] = hh;
                if (USE_LO) h0l[idx] = f2bf(h - bf2f(hh));
                if (s == Tt - 1) {
                    out[16777216 + cb * Hh + cu] = h;          // h_n[0]
                    out[16777216 + 65536 + cb * Hh + cu] = c;  // c_n[0]
                }
            }
        } else {                            // ---- layer 1 epilogue, t = s-1 ----
            if (s >= 1) {
                const int t = s - 1;
                float vi = bi, vf = bf_, vg = bg, vo = bo;
                #pragma unroll
                for (int w = 0; w < 4; ++w) {
                    vi += red[1][w][cb][ca];
                    vf += red[1][w][cb][4 + ca];
                    vg += red[1][w][cb][8 + ca];
                    vo += red[1][w][cb][12 + ca];
                }
                float ig = sigm(vi), fg = sigm(vf), gg = tanh_f(vg), og = sigm(vo);
                c = fg * c + ig * gg;
                float h = og * tanh_f(c);
                size_t idx = parROff + (size_t)cb * Hh + cu;
                unsigned short hh = f2bf(h);
                h1h[idx] = hh;
                if (USE_LO) h1l[idx] = f2bf(h - bf2f(hh));
                out[(size_t)cb * (Tt * Hh) + (size_t)t * Hh + cu] = h;   // y1
                if (s == Tt) {
                    out[16777216 + 32768 + cb * Hh + cu] = h;            // h_n[1]
                    out[16777216 + 65536 + 32768 + cb * Hh + cu] = c;    // c_n[1]
                }
            }
        }

        if (s < Tt) {
            __threadfence();                 // release our h writes (device scope)
            __syncthreads();
            if (tid == 0) {
                __hip_atomic_fetch_add(counter, 1u, __ATOMIC_RELEASE, __HIP_MEMORY_SCOPE_AGENT);
                const unsigned target = (unsigned)NWG * (unsigned)(s + 1);
                while (__hip_atomic_load(counter, __ATOMIC_RELAXED, __HIP_MEMORY_SCOPE_AGENT) < target) {
                    __builtin_amdgcn_s_sleep(1);
                }
            }
            __syncthreads();
            __threadfence();                 // acquire before next-step reads
        }
    }
}

extern "C" void kernel_launch(void* const* d_in, const int* in_sizes, int n_in,
                              void* d_out, int out_size, void* d_ws, size_t ws_size,
                              hipStream_t stream) {
    const float* x     = (const float*)d_in[0];
    const float* w_ih0 = (const float*)d_in[1];
    const float* w_hh0 = (const float*)d_in[2];
    const float* b0    = (const float*)d_in[3];
    const float* w_ih1 = (const float*)d_in[4];
    const float* w_hh1 = (const float*)d_in[5];
    const float* b1    = (const float*)d_in[6];
    float* out = (float*)d_out;

    const size_t SZ_WARRH = 33554432;   // 4*256*16*1024*2
    const size_t SZ_WARRL = 16777216;   // 2*256*16*1024*2
    const size_t SZ_XT    = 33619968;   // 513*32*1024*2
    const size_t SZ_H     = 131072;     // 2*32*1024*2

    char* ws = (char*)d_ws;
    unsigned short* warrh = (unsigned short*)ws;
    unsigned short* warrl = (unsigned short*)(ws + SZ_WARRH);
    unsigned short* xTh   = (unsigned short*)(ws + SZ_WARRH + SZ_WARRL);
    unsigned short* xTl   = (unsigned short*)(ws + SZ_WARRH + SZ_WARRL + SZ_XT);
    char* zbase = ws + SZ_WARRH + SZ_WARRL + 2 * SZ_XT;
    unsigned short* h0h = (unsigned short*)zbase;
    unsigned short* h0l = (unsigned short*)(zbase + SZ_H);
    unsigned short* h1h = (unsigned short*)(zbase + 2 * SZ_H);
    unsigned short* h1l = (unsigned short*)(zbase + 3 * SZ_H);
    unsigned int* counter = (unsigned int*)(zbase + 4 * SZ_H);

    const size_t FULL = SZ_WARRH + SZ_WARRL + 2 * SZ_XT + 4 * SZ_H + 256;
    const bool use_lo = ws_size >= FULL;

    hipMemsetAsync(zbase, 0, 4 * SZ_H + 256, stream);
    hipLaunchKernelGGL(k_xT,   dim3(16416), dim3(256), 0, stream, x, xTh, xTl, (int)use_lo);
    hipLaunchKernelGGL(k_warr, dim3(1024),  dim3(256), 0, stream,
                       w_ih0, w_hh0, w_ih1, w_hh1, warrh, warrl, (int)use_lo);
    if (use_lo) {
        hipLaunchKernelGGL(k_lstm<true>, dim3(256), dim3(256), 0, stream,
                           xTh, xTl, warrh, warrl, h0h, h0l, h1h, h1l, counter, b0, b1, out);
    } else {
        hipLaunchKernelGGL(k_lstm<false>, dim3(256), dim3(256), 0, stream,
                           xTh, xTl, warrh, warrl, h0h, h0l, h1h, h1l, counter, b0, b1, out);
    }
}

// Round 5
// 13270.476 us; speedup vs baseline: 2.4413x; 2.4413x over previous
//
#include <hip/hip_runtime.h>
#include <hip/hip_bf16.h>

// ---------------------------------------------------------------------------
// 2-layer LSTM, B=32, T=512, H=1024, fp32 in/out.
// Round 5: fence-free coherence via COMPILER-VISIBLE relaxed agent atomics
//   (no hand-rolled memory asm; compiler emits sc0/sc1 + correct waitcnts).
//   - h state: __hip_atomic relaxed AGENT loads (8B, staged) / stores (2B).
//   - No __threadfence anywhere (round 3's 63us/step was L2 wb+inv per step);
//     release = s_waitcnt vmcnt(0) + __syncthreads before flag store.
//   - Symmetric distributed flag barrier: wg i stores step into its own 128B
//     line; ALL wgs poll all 256 flags (thread tid polls wg tid) with
//     __syncthreads_and. No wg0 aggregator, no atomic RMW.
//   - Weights/xT: normal cached loads (L2-resident, never invalidated);
//     weight fragments opacity-pinned in registers.
//   Numerics identical to round 3 (passed, absmax 0.0547).
// ---------------------------------------------------------------------------

constexpr int Hh = 1024;
constexpr int Bb = 32;
constexpr int Tt = 512;
constexpr int NWG = 256;

typedef float f32x4 __attribute__((ext_vector_type(4)));
typedef int   i32x4 __attribute__((ext_vector_type(4)));

__device__ inline void mfma_bf16(f32x4& acc, i32x4 a, i32x4 b) {
    // s_nop 2 guards compiler-inserted VALU writes before the MFMA reads.
    asm("s_nop 2\n\tv_mfma_f32_16x16x32_bf16 %0, %1, %2, %0"
        : "+v"(acc) : "v"(a), "v"(b));
}

// Coherent (cross-XCD) 16B fragment load: two relaxed agent 8B atomic loads.
// Compiler emits global_load_dwordx2 with sc bits and proper waitcnts.
__device__ inline i32x4 aload_x4(const unsigned short* p) {
    const unsigned long long* q = (const unsigned long long*)p;
    unsigned long long a = __hip_atomic_load(q,     __ATOMIC_RELAXED, __HIP_MEMORY_SCOPE_AGENT);
    unsigned long long b = __hip_atomic_load(q + 1, __ATOMIC_RELAXED, __HIP_MEMORY_SCOPE_AGENT);
    i32x4 r;
    r[0] = (int)(unsigned)a; r[1] = (int)(a >> 32);
    r[2] = (int)(unsigned)b; r[3] = (int)(b >> 32);
    return r;
}
__device__ inline void astore_u16(unsigned short* p, unsigned short v) {
    __hip_atomic_store(p, v, __ATOMIC_RELAXED, __HIP_MEMORY_SCOPE_AGENT);
}

__device__ inline unsigned short f2bf(float f) {
    unsigned u = __float_as_uint(f);
    u += 0x7fffu + ((u >> 16) & 1u);   // round-to-nearest-even
    return (unsigned short)(u >> 16);
}
__device__ inline float bf2f(unsigned short s) {
    return __uint_as_float((unsigned)s << 16);
}

__device__ inline float sigm(float x)  { return 1.f / (1.f + __expf(-x)); }
__device__ inline float tanh_f(float x){ return 1.f - 2.f / (__expf(2.f * x) + 1.f); }

// x [32][512][1024] f32 -> xT hi/lo [513][32][1024] bf16 (slot 512 zeroed)
__global__ __launch_bounds__(256) void k_xT(const float* __restrict__ x,
                                            unsigned short* __restrict__ xh,
                                            unsigned short* __restrict__ xl,
                                            int use_lo) {
    int bid = blockIdx.x;               // 0..16415
    int t = bid >> 5, b = bid & 31;
    size_t o = ((size_t)t * Bb + b) * Hh;
    if (t == Tt) {
        ushort4 z = {0, 0, 0, 0};
        ((ushort4*)(xh + o))[threadIdx.x] = z;
        if (use_lo) ((ushort4*)(xl + o))[threadIdx.x] = z;
        return;
    }
    const float4* src = (const float4*)(x + ((size_t)b * Tt + t) * Hh);
    float4 v = src[threadIdx.x];
    ushort4 hi;
    hi.x = f2bf(v.x); hi.y = f2bf(v.y); hi.z = f2bf(v.z); hi.w = f2bf(v.w);
    ((ushort4*)(xh + o))[threadIdx.x] = hi;
    if (use_lo) {
        ushort4 lo;
        lo.x = f2bf(v.x - bf2f(hi.x));
        lo.y = f2bf(v.y - bf2f(hi.y));
        lo.z = f2bf(v.z - bf2f(hi.z));
        lo.w = f2bf(v.w - bf2f(hi.w));
        ((ushort4*)(xl + o))[threadIdx.x] = lo;
    }
}

// W[mat] [1024][4096] f32 -> wh[mat][wg][col(16)][k(1024)] bf16 (4 mats),
// lo planes only for mats 0,2 (w_ih0, w_ih1) packed at lo-slot mat>>1.
__global__ __launch_bounds__(256) void k_warr(const float* __restrict__ w0,
                                              const float* __restrict__ w1,
                                              const float* __restrict__ w2,
                                              const float* __restrict__ w3,
                                              unsigned short* __restrict__ wh,
                                              unsigned short* __restrict__ wl,
                                              int use_lo) {
    int bid = blockIdx.x;               // 0..1023
    int mat = bid >> 8, wg = bid & 255;
    const float* W = (mat == 0) ? w0 : (mat == 1) ? w1 : (mat == 2) ? w2 : w3;
    size_t dbase = ((size_t)(mat * NWG + wg) * 16) * Hh;
    size_t dlo   = ((size_t)(((mat >> 1) & 1) * NWG + wg) * 16) * Hh;
    const bool want_lo = use_lo && ((mat & 1) == 0);
    for (int it = 0; it < 64; ++it) {
        int idx = it * 256 + (int)threadIdx.x;
        int col = idx >> 10, k = idx & 1023;
        int cg = (col >> 2) * Hh + wg * 4 + (col & 3);
        float w = W[(size_t)k * 4096 + cg];
        unsigned short hi = f2bf(w);
        wh[dbase + (size_t)col * Hh + k] = hi;
        if (want_lo) wl[dlo + (size_t)col * Hh + k] = f2bf(w - bf2f(hi));
    }
}

template <bool USE_LO>
__global__ __launch_bounds__(256, 1) void k_lstm(
    const unsigned short* __restrict__ xTh,
    const unsigned short* __restrict__ xTl,
    const unsigned short* __restrict__ warrh,
    const unsigned short* __restrict__ warrl,
    unsigned short* __restrict__ h0h, unsigned short* __restrict__ h0l,
    unsigned short* __restrict__ h1h, unsigned short* __restrict__ h1l,
    unsigned int*   __restrict__ flags,    // [256] lines of 32 u32
    const float* __restrict__ b0,
    const float* __restrict__ b1,
    float* __restrict__ out)
{
    __shared__ float red[2][4][32][17];     // [layer][wave][batch(row)][col(+pad)]

    const int tid  = threadIdx.x;
    const int wave = tid >> 6;
    const int l    = tid & 63;
    const int wg   = blockIdx.x;

    // ---- persistent B fragments (weights) in registers ----
    i32x4 Bih0h[8], Bhh0h[8], Bih1h[8], Bhh1h[8];
    i32x4 Bih0l[8], Bih1l[8];
    {
        const size_t matStride = (size_t)NWG * 16 * Hh;
        const size_t wgOff = (size_t)wg * 16 * Hh;
        const int laneOff = (l & 15) * Hh + ((l >> 4) * 8);
        #pragma unroll
        for (int kk = 0; kk < 8; ++kk) {
            int off = laneOff + wave * 256 + kk * 32;
            Bih0h[kk] = *(const i32x4*)(warrh + 0 * matStride + wgOff + off);
            Bhh0h[kk] = *(const i32x4*)(warrh + 1 * matStride + wgOff + off);
            Bih1h[kk] = *(const i32x4*)(warrh + 2 * matStride + wgOff + off);
            Bhh1h[kk] = *(const i32x4*)(warrh + 3 * matStride + wgOff + off);
            if (USE_LO) {
                Bih0l[kk] = *(const i32x4*)(warrl + 0 * matStride + wgOff + off);
                Bih1l[kk] = *(const i32x4*)(warrl + 1 * matStride + wgOff + off);
            }
        }
        // Opacity: values no longer "pure loads" -> cannot be rematerialized.
        #pragma unroll
        for (int kk = 0; kk < 8; ++kk) {
            asm volatile("" : "+v"(Bih0h[kk]), "+v"(Bhh0h[kk]),
                             "+v"(Bih1h[kk]), "+v"(Bhh1h[kk]));
            if (USE_LO)
                asm volatile("" : "+v"(Bih0l[kk]), "+v"(Bih1l[kk]));
        }
    }

    // ---- epilogue cell ownership: tid<128 -> layer0, tid>=128 -> layer1 ----
    const int cid = tid & 127;
    const int cb  = cid & 31;          // batch
    const int ca  = (cid >> 5) & 3;    // local unit
    const int cu  = wg * 4 + ca;       // global hidden unit
    const float* bias = (tid < 128) ? b0 : b1;
    const float bi  = bias[cu];
    const float bf_ = bias[Hh + cu];
    const float bg  = bias[2 * Hh + cu];
    const float bo  = bias[3 * Hh + cu];
    float c = 0.f;

    const int laneA = (l & 15) * Hh + ((l >> 4) * 8);

    for (int s = 0; s <= Tt; ++s) {
        const int par_w = s & 1;
        const int par_r = par_w ^ 1;
        const size_t stepOff = (size_t)s * (Bb * Hh);
        const size_t parROff = (size_t)par_r * (Bb * Hh);
        const size_t parWOff = (size_t)par_w * (Bb * Hh);
        const unsigned short* xph  = xTh + stepOff;
        const unsigned short* xpl  = xTl + stepOff;
        const unsigned short* h0rh = h0h + parROff;
        const unsigned short* h0rl = h0l + parROff;
        const unsigned short* h1rh = h1h + parWOff;
        const unsigned short* h1rl = h1l + parWOff;

        f32x4 a00 = {0,0,0,0}, a01 = {0,0,0,0}, a10 = {0,0,0,0}, a11 = {0,0,0,0};

        #pragma unroll
        for (int m = 0; m < 2; ++m) {
            f32x4& acc0 = m ? a01 : a00;
            f32x4& acc1 = m ? a11 : a10;

            // stage this half's h fragments from the coherent point
            i32x4 g0hv[8], g1hv[8], g0lv[8], g1lv[8];
            #pragma unroll
            for (int kk = 0; kk < 8; ++kk) {
                const int off = laneA + m * 16 * Hh + wave * 256 + kk * 32;
                g0hv[kk] = aload_x4(h0rh + off);
                g1hv[kk] = aload_x4(h1rh + off);
                if (USE_LO) {
                    g0lv[kk] = aload_x4(h0rl + off);
                    g1lv[kk] = aload_x4(h1rl + off);
                }
            }

            #pragma unroll
            for (int kk = 0; kk < 8; ++kk) {
                const int off = laneA + m * 16 * Hh + wave * 256 + kk * 32;
                i32x4 axh = *(const i32x4*)(xph + off);      // cached loads
                mfma_bf16(acc0, axh,      Bih0h[kk]);
                mfma_bf16(acc0, g0hv[kk], Bhh0h[kk]);
                mfma_bf16(acc1, g0hv[kk], Bih1h[kk]);
                mfma_bf16(acc1, g1hv[kk], Bhh1h[kk]);
                if (USE_LO) {
                    i32x4 axl = *(const i32x4*)(xpl + off);
                    mfma_bf16(acc0, axh,      Bih0l[kk]);   // x * dWih0
                    mfma_bf16(acc0, axl,      Bih0h[kk]);   // dx * Wih0
                    mfma_bf16(acc0, g0lv[kk], Bhh0h[kk]);   // dh0 * Whh0
                    mfma_bf16(acc1, g0hv[kk], Bih1l[kk]);   // y0 * dWih1
                    mfma_bf16(acc1, g0lv[kk], Bih1h[kk]);   // dy0 * Wih1
                    mfma_bf16(acc1, g1lv[kk], Bhh1h[kk]);   // dh1 * Whh1
                }
            }
        }
        asm("s_nop 7\n\ts_nop 7" : "+v"(a00), "+v"(a01), "+v"(a10), "+v"(a11)); // MFMA->VALU hazard

        {
            const int r0 = (l >> 4) * 4;   // C/D: col=lane&15, row=(lane>>4)*4+reg [m89]
            const int cc = l & 15;
            #pragma unroll
            for (int r = 0; r < 4; ++r) {
                red[0][wave][r0 + r][cc]      = a00[r];
                red[0][wave][16 + r0 + r][cc] = a01[r];
                red[1][wave][r0 + r][cc]      = a10[r];
                red[1][wave][16 + r0 + r][cc] = a11[r];
            }
        }
        __syncthreads();

        if (tid < 128) {                    // ---- layer 0 epilogue, t = s ----
            if (s < Tt) {
                float vi = bi, vf = bf_, vg = bg, vo = bo;
                #pragma unroll
                for (int w = 0; w < 4; ++w) {
                    vi += red[0][w][cb][ca];
                    vf += red[0][w][cb][4 + ca];
                    vg += red[0][w][cb][8 + ca];
                    vo += red[0][w][cb][12 + ca];
                }
                float ig = sigm(vi), fg = sigm(vf), gg = tanh_f(vg), og = sigm(vo);
                c = fg * c + ig * gg;
                float h = og * tanh_f(c);
                size_t idx = parWOff + (size_t)cb * Hh + cu;
                unsigned short hh = f2bf(h);
                astore_u16(h0h + idx, hh);
                if (USE_LO) astore_u16(h0l + idx, f2bf(h - bf2f(hh)));
                if (s == Tt - 1) {
                    out[16777216 + cb * Hh + cu] = h;          // h_n[0]
                    out[16777216 + 65536 + cb * Hh + cu] = c;  // c_n[0]
                }
            }
        } else {                            // ---- layer 1 epilogue, t = s-1 ----
            if (s >= 1) {
                const int t = s - 1;
                float vi = bi, vf = bf_, vg = bg, vo = bo;
                #pragma unroll
                for (int w = 0; w < 4; ++w) {
                    vi += red[1][w][cb][ca];
                    vf += red[1][w][cb][4 + ca];
                    vg += red[1][w][cb][8 + ca];
                    vo += red[1][w][cb][12 + ca];
                }
                float ig = sigm(vi), fg = sigm(vf), gg = tanh_f(vg), og = sigm(vo);
                c = fg * c + ig * gg;
                float h = og * tanh_f(c);
                size_t idx = parROff + (size_t)cb * Hh + cu;
                unsigned short hh = f2bf(h);
                astore_u16(h1h + idx, hh);
                if (USE_LO) astore_u16(h1l + idx, f2bf(h - bf2f(hh)));
                out[(size_t)cb * (Tt * Hh) + (size_t)t * Hh + cu] = h;   // y1
                if (s == Tt) {
                    out[16777216 + 32768 + cb * Hh + cu] = h;            // h_n[1]
                    out[16777216 + 65536 + 32768 + cb * Hh + cu] = c;    // c_n[1]
                }
            }
        }

        // ---- fence-free symmetric flag barrier ----
        if (s < Tt) {
            const unsigned tgt = (unsigned)(s + 1);
            asm volatile("s_waitcnt vmcnt(0)" ::: "memory");  // own h stores at coherence point
            __syncthreads();                                  // all threads' stores drained
            if (tid == 0)
                __hip_atomic_store(flags + (size_t)wg * 32, tgt,
                                   __ATOMIC_RELAXED, __HIP_MEMORY_SCOPE_AGENT);
            int ok = 0;
            do {
                unsigned f = __hip_atomic_load(flags + (size_t)tid * 32,
                                               __ATOMIC_RELAXED, __HIP_MEMORY_SCOPE_AGENT);
                ok = __syncthreads_and((int)(f >= tgt));
                if (!ok) __builtin_amdgcn_s_sleep(2);
            } while (!ok);
        }
    }
}

extern "C" void kernel_launch(void* const* d_in, const int* in_sizes, int n_in,
                              void* d_out, int out_size, void* d_ws, size_t ws_size,
                              hipStream_t stream) {
    const float* x     = (const float*)d_in[0];
    const float* w_ih0 = (const float*)d_in[1];
    const float* w_hh0 = (const float*)d_in[2];
    const float* b0    = (const float*)d_in[3];
    const float* w_ih1 = (const float*)d_in[4];
    const float* w_hh1 = (const float*)d_in[5];
    const float* b1    = (const float*)d_in[6];
    float* out = (float*)d_out;

    const size_t SZ_WARRH = 33554432;   // 4*256*16*1024*2
    const size_t SZ_WARRL = 16777216;   // 2*256*16*1024*2
    const size_t SZ_XT    = 33619968;   // 513*32*1024*2
    const size_t SZ_H     = 131072;     // 2*32*1024*2
    const size_t SZ_FLAGS = 32768;      // 256 lines x 128B

    char* ws = (char*)d_ws;
    unsigned short* warrh = (unsigned short*)ws;
    unsigned short* warrl = (unsigned short*)(ws + SZ_WARRH);
    unsigned short* xTh   = (unsigned short*)(ws + SZ_WARRH + SZ_WARRL);
    unsigned short* xTl   = (unsigned short*)(ws + SZ_WARRH + SZ_WARRL + SZ_XT);
    char* zbase = ws + SZ_WARRH + SZ_WARRL + 2 * SZ_XT;
    unsigned short* h0h = (unsigned short*)zbase;
    unsigned short* h0l = (unsigned short*)(zbase + SZ_H);
    unsigned short* h1h = (unsigned short*)(zbase + 2 * SZ_H);
    unsigned short* h1l = (unsigned short*)(zbase + 3 * SZ_H);
    unsigned int* flags = (unsigned int*)(zbase + 4 * SZ_H);

    const size_t FULL = SZ_WARRH + SZ_WARRL + 2 * SZ_XT + 4 * SZ_H + SZ_FLAGS;
    const bool use_lo = ws_size >= FULL;

    hipMemsetAsync(zbase, 0, 4 * SZ_H + SZ_FLAGS, stream);   // h planes + flags, every launch (replay-safe)
    hipLaunchKernelGGL(k_xT,   dim3(16416), dim3(256), 0, stream, x, xTh, xTl, (int)use_lo);
    hipLaunchKernelGGL(k_warr, dim3(1024),  dim3(256), 0, stream,
                       w_ih0, w_hh0, w_ih1, w_hh1, warrh, warrl, (int)use_lo);
    if (use_lo) {
        hipLaunchKernelGGL(k_lstm<true>, dim3(256), dim3(256), 0, stream,
                           xTh, xTl, warrh, warrl, h0h, h0l, h1h, h1l, flags, b0, b1, out);
    } else {
        hipLaunchKernelGGL(k_lstm<false>, dim3(256), dim3(256), 0, stream,
                           xTh, xTl, warrh, warrl, h0h, h0l, h1h, h1l, flags, b0, b1, out);
    }
}

// Round 6
// 13019.275 us; speedup vs baseline: 2.4884x; 1.0193x over previous
//
#include <hip/hip_runtime.h>
#include <hip/hip_bf16.h>

// ---------------------------------------------------------------------------
// 2-layer LSTM, B=32, T=512, H=1024, fp32 in/out.
// Round 6: barrier redesign ONLY (MFMA core/geometry/numerics = round 5,
//   which passed at absmax 0.0547).
//   Round-5 barrier had ALL 65536 threads UC-polling 256 flag lines
//   continuously -> request storm at the coherence point that also starves
//   the h-state UC loads. New barrier:
//     arrival:  wg tid0 UC-stores step to its own 128B line (after vmcnt(0)
//               + syncthreads release),
//     aggregate: wg0's 256 threads poll one flag each (syncthreads_and loop),
//               tid0 then UC-stores a single `go` word,
//     release:  all other wgs poll `go` with ONE thread + s_sleep, then
//               __syncthreads.
//   Poll traffic drops ~500x. Flags/go monotonic, memset-zeroed per launch.
// ---------------------------------------------------------------------------

constexpr int Hh = 1024;
constexpr int Bb = 32;
constexpr int Tt = 512;
constexpr int NWG = 256;

typedef float f32x4 __attribute__((ext_vector_type(4)));
typedef int   i32x4 __attribute__((ext_vector_type(4)));

__device__ inline void mfma_bf16(f32x4& acc, i32x4 a, i32x4 b) {
    // s_nop 2 guards compiler-inserted VALU writes before the MFMA reads.
    asm("s_nop 2\n\tv_mfma_f32_16x16x32_bf16 %0, %1, %2, %0"
        : "+v"(acc) : "v"(a), "v"(b));
}

// Coherent (cross-XCD) 16B fragment load: two relaxed agent 8B atomic loads.
__device__ inline i32x4 aload_x4(const unsigned short* p) {
    const unsigned long long* q = (const unsigned long long*)p;
    unsigned long long a = __hip_atomic_load(q,     __ATOMIC_RELAXED, __HIP_MEMORY_SCOPE_AGENT);
    unsigned long long b = __hip_atomic_load(q + 1, __ATOMIC_RELAXED, __HIP_MEMORY_SCOPE_AGENT);
    i32x4 r;
    r[0] = (int)(unsigned)a; r[1] = (int)(a >> 32);
    r[2] = (int)(unsigned)b; r[3] = (int)(b >> 32);
    return r;
}
__device__ inline void astore_u16(unsigned short* p, unsigned short v) {
    __hip_atomic_store(p, v, __ATOMIC_RELAXED, __HIP_MEMORY_SCOPE_AGENT);
}

__device__ inline unsigned short f2bf(float f) {
    unsigned u = __float_as_uint(f);
    u += 0x7fffu + ((u >> 16) & 1u);   // round-to-nearest-even
    return (unsigned short)(u >> 16);
}
__device__ inline float bf2f(unsigned short s) {
    return __uint_as_float((unsigned)s << 16);
}

__device__ inline float sigm(float x)  { return 1.f / (1.f + __expf(-x)); }
__device__ inline float tanh_f(float x){ return 1.f - 2.f / (__expf(2.f * x) + 1.f); }

// x [32][512][1024] f32 -> xT hi/lo [513][32][1024] bf16 (slot 512 zeroed)
__global__ __launch_bounds__(256) void k_xT(const float* __restrict__ x,
                                            unsigned short* __restrict__ xh,
                                            unsigned short* __restrict__ xl,
                                            int use_lo) {
    int bid = blockIdx.x;               // 0..16415
    int t = bid >> 5, b = bid & 31;
    size_t o = ((size_t)t * Bb + b) * Hh;
    if (t == Tt) {
        ushort4 z = {0, 0, 0, 0};
        ((ushort4*)(xh + o))[threadIdx.x] = z;
        if (use_lo) ((ushort4*)(xl + o))[threadIdx.x] = z;
        return;
    }
    const float4* src = (const float4*)(x + ((size_t)b * Tt + t) * Hh);
    float4 v = src[threadIdx.x];
    ushort4 hi;
    hi.x = f2bf(v.x); hi.y = f2bf(v.y); hi.z = f2bf(v.z); hi.w = f2bf(v.w);
    ((ushort4*)(xh + o))[threadIdx.x] = hi;
    if (use_lo) {
        ushort4 lo;
        lo.x = f2bf(v.x - bf2f(hi.x));
        lo.y = f2bf(v.y - bf2f(hi.y));
        lo.z = f2bf(v.z - bf2f(hi.z));
        lo.w = f2bf(v.w - bf2f(hi.w));
        ((ushort4*)(xl + o))[threadIdx.x] = lo;
    }
}

// W[mat] [1024][4096] f32 -> wh[mat][wg][col(16)][k(1024)] bf16 (4 mats),
// lo planes only for mats 0,2 (w_ih0, w_ih1) packed at lo-slot mat>>1.
__global__ __launch_bounds__(256) void k_warr(const float* __restrict__ w0,
                                              const float* __restrict__ w1,
                                              const float* __restrict__ w2,
                                              const float* __restrict__ w3,
                                              unsigned short* __restrict__ wh,
                                              unsigned short* __restrict__ wl,
                                              int use_lo) {
    int bid = blockIdx.x;               // 0..1023
    int mat = bid >> 8, wg = bid & 255;
    const float* W = (mat == 0) ? w0 : (mat == 1) ? w1 : (mat == 2) ? w2 : w3;
    size_t dbase = ((size_t)(mat * NWG + wg) * 16) * Hh;
    size_t dlo   = ((size_t)(((mat >> 1) & 1) * NWG + wg) * 16) * Hh;
    const bool want_lo = use_lo && ((mat & 1) == 0);
    for (int it = 0; it < 64; ++it) {
        int idx = it * 256 + (int)threadIdx.x;
        int col = idx >> 10, k = idx & 1023;
        int cg = (col >> 2) * Hh + wg * 4 + (col & 3);
        float w = W[(size_t)k * 4096 + cg];
        unsigned short hi = f2bf(w);
        wh[dbase + (size_t)col * Hh + k] = hi;
        if (want_lo) wl[dlo + (size_t)col * Hh + k] = f2bf(w - bf2f(hi));
    }
}

template <bool USE_LO>
__global__ __launch_bounds__(256, 1) void k_lstm(
    const unsigned short* __restrict__ xTh,
    const unsigned short* __restrict__ xTl,
    const unsigned short* __restrict__ warrh,
    const unsigned short* __restrict__ warrl,
    unsigned short* __restrict__ h0h, unsigned short* __restrict__ h0l,
    unsigned short* __restrict__ h1h, unsigned short* __restrict__ h1l,
    unsigned int*   __restrict__ flags,    // [256] lines of 32 u32 + go line
    const float* __restrict__ b0,
    const float* __restrict__ b1,
    float* __restrict__ out)
{
    __shared__ float red[2][4][32][17];     // [layer][wave][batch(row)][col(+pad)]

    const int tid  = threadIdx.x;
    const int wave = tid >> 6;
    const int l    = tid & 63;
    const int wg   = blockIdx.x;
    unsigned* go = flags + 8192;            // byte offset 32768

    // ---- persistent B fragments (weights) in registers ----
    i32x4 Bih0h[8], Bhh0h[8], Bih1h[8], Bhh1h[8];
    i32x4 Bih0l[8], Bih1l[8];
    {
        const size_t matStride = (size_t)NWG * 16 * Hh;
        const size_t wgOff = (size_t)wg * 16 * Hh;
        const int laneOff = (l & 15) * Hh + ((l >> 4) * 8);
        #pragma unroll
        for (int kk = 0; kk < 8; ++kk) {
            int off = laneOff + wave * 256 + kk * 32;
            Bih0h[kk] = *(const i32x4*)(warrh + 0 * matStride + wgOff + off);
            Bhh0h[kk] = *(const i32x4*)(warrh + 1 * matStride + wgOff + off);
            Bih1h[kk] = *(const i32x4*)(warrh + 2 * matStride + wgOff + off);
            Bhh1h[kk] = *(const i32x4*)(warrh + 3 * matStride + wgOff + off);
            if (USE_LO) {
                Bih0l[kk] = *(const i32x4*)(warrl + 0 * matStride + wgOff + off);
                Bih1l[kk] = *(const i32x4*)(warrl + 1 * matStride + wgOff + off);
            }
        }
        // Opacity: values no longer "pure loads" -> cannot be rematerialized.
        #pragma unroll
        for (int kk = 0; kk < 8; ++kk) {
            asm volatile("" : "+v"(Bih0h[kk]), "+v"(Bhh0h[kk]),
                             "+v"(Bih1h[kk]), "+v"(Bhh1h[kk]));
            if (USE_LO)
                asm volatile("" : "+v"(Bih0l[kk]), "+v"(Bih1l[kk]));
        }
    }

    // ---- epilogue cell ownership: tid<128 -> layer0, tid>=128 -> layer1 ----
    const int cid = tid & 127;
    const int cb  = cid & 31;          // batch
    const int ca  = (cid >> 5) & 3;    // local unit
    const int cu  = wg * 4 + ca;       // global hidden unit
    const float* bias = (tid < 128) ? b0 : b1;
    const float bi  = bias[cu];
    const float bf_ = bias[Hh + cu];
    const float bg  = bias[2 * Hh + cu];
    const float bo  = bias[3 * Hh + cu];
    float c = 0.f;

    const int laneA = (l & 15) * Hh + ((l >> 4) * 8);

    for (int s = 0; s <= Tt; ++s) {
        const int par_w = s & 1;
        const int par_r = par_w ^ 1;
        const size_t stepOff = (size_t)s * (Bb * Hh);
        const size_t parROff = (size_t)par_r * (Bb * Hh);
        const size_t parWOff = (size_t)par_w * (Bb * Hh);
        const unsigned short* xph  = xTh + stepOff;
        const unsigned short* xpl  = xTl + stepOff;
        const unsigned short* h0rh = h0h + parROff;
        const unsigned short* h0rl = h0l + parROff;
        const unsigned short* h1rh = h1h + parWOff;
        const unsigned short* h1rl = h1l + parWOff;

        f32x4 a00 = {0,0,0,0}, a01 = {0,0,0,0}, a10 = {0,0,0,0}, a11 = {0,0,0,0};

        #pragma unroll
        for (int m = 0; m < 2; ++m) {
            f32x4& acc0 = m ? a01 : a00;
            f32x4& acc1 = m ? a11 : a10;

            // stage this half's h fragments from the coherent point
            i32x4 g0hv[8], g1hv[8], g0lv[8], g1lv[8];
            #pragma unroll
            for (int kk = 0; kk < 8; ++kk) {
                const int off = laneA + m * 16 * Hh + wave * 256 + kk * 32;
                g0hv[kk] = aload_x4(h0rh + off);
                g1hv[kk] = aload_x4(h1rh + off);
                if (USE_LO) {
                    g0lv[kk] = aload_x4(h0rl + off);
                    g1lv[kk] = aload_x4(h1rl + off);
                }
            }

            #pragma unroll
            for (int kk = 0; kk < 8; ++kk) {
                const int off = laneA + m * 16 * Hh + wave * 256 + kk * 32;
                i32x4 axh = *(const i32x4*)(xph + off);      // cached loads
                mfma_bf16(acc0, axh,      Bih0h[kk]);
                mfma_bf16(acc0, g0hv[kk], Bhh0h[kk]);
                mfma_bf16(acc1, g0hv[kk], Bih1h[kk]);
                mfma_bf16(acc1, g1hv[kk], Bhh1h[kk]);
                if (USE_LO) {
                    i32x4 axl = *(const i32x4*)(xpl + off);
                    mfma_bf16(acc0, axh,      Bih0l[kk]);   // x * dWih0
                    mfma_bf16(acc0, axl,      Bih0h[kk]);   // dx * Wih0
                    mfma_bf16(acc0, g0lv[kk], Bhh0h[kk]);   // dh0 * Whh0
                    mfma_bf16(acc1, g0hv[kk], Bih1l[kk]);   // y0 * dWih1
                    mfma_bf16(acc1, g0lv[kk], Bih1h[kk]);   // dy0 * Wih1
                    mfma_bf16(acc1, g1lv[kk], Bhh1h[kk]);   // dh1 * Whh1
                }
            }
        }
        asm("s_nop 7\n\ts_nop 7" : "+v"(a00), "+v"(a01), "+v"(a10), "+v"(a11)); // MFMA->VALU hazard

        {
            const int r0 = (l >> 4) * 4;   // C/D: col=lane&15, row=(lane>>4)*4+reg [m89]
            const int cc = l & 15;
            #pragma unroll
            for (int r = 0; r < 4; ++r) {
                red[0][wave][r0 + r][cc]      = a00[r];
                red[0][wave][16 + r0 + r][cc] = a01[r];
                red[1][wave][r0 + r][cc]      = a10[r];
                red[1][wave][16 + r0 + r][cc] = a11[r];
            }
        }
        __syncthreads();

        if (tid < 128) {                    // ---- layer 0 epilogue, t = s ----
            if (s < Tt) {
                float vi = bi, vf = bf_, vg = bg, vo = bo;
                #pragma unroll
                for (int w = 0; w < 4; ++w) {
                    vi += red[0][w][cb][ca];
                    vf += red[0][w][cb][4 + ca];
                    vg += red[0][w][cb][8 + ca];
                    vo += red[0][w][cb][12 + ca];
                }
                float ig = sigm(vi), fg = sigm(vf), gg = tanh_f(vg), og = sigm(vo);
                c = fg * c + ig * gg;
                float h = og * tanh_f(c);
                size_t idx = parWOff + (size_t)cb * Hh + cu;
                unsigned short hh = f2bf(h);
                astore_u16(h0h + idx, hh);
                if (USE_LO) astore_u16(h0l + idx, f2bf(h - bf2f(hh)));
                if (s == Tt - 1) {
                    out[16777216 + cb * Hh + cu] = h;          // h_n[0]
                    out[16777216 + 65536 + cb * Hh + cu] = c;  // c_n[0]
                }
            }
        } else {                            // ---- layer 1 epilogue, t = s-1 ----
            if (s >= 1) {
                const int t = s - 1;
                float vi = bi, vf = bf_, vg = bg, vo = bo;
                #pragma unroll
                for (int w = 0; w < 4; ++w) {
                    vi += red[1][w][cb][ca];
                    vf += red[1][w][cb][4 + ca];
                    vg += red[1][w][cb][8 + ca];
                    vo += red[1][w][cb][12 + ca];
                }
                float ig = sigm(vi), fg = sigm(vf), gg = tanh_f(vg), og = sigm(vo);
                c = fg * c + ig * gg;
                float h = og * tanh_f(c);
                size_t idx = parROff + (size_t)cb * Hh + cu;
                unsigned short hh = f2bf(h);
                astore_u16(h1h + idx, hh);
                if (USE_LO) astore_u16(h1l + idx, f2bf(h - bf2f(hh)));
                out[(size_t)cb * (Tt * Hh) + (size_t)t * Hh + cu] = h;   // y1
                if (s == Tt) {
                    out[16777216 + 32768 + cb * Hh + cu] = h;            // h_n[1]
                    out[16777216 + 65536 + 32768 + cb * Hh + cu] = c;    // c_n[1]
                }
            }
        }

        // ---- low-traffic barrier: arrivals -> wg0 aggregates -> go word ----
        if (s < Tt) {
            const unsigned tgt = (unsigned)(s + 1);
            asm volatile("s_waitcnt vmcnt(0)" ::: "memory");  // own h stores at coherence point
            __syncthreads();                                  // all threads' stores drained
            if (wg == 0) {
                if (tid == 0)
                    __hip_atomic_store(flags, tgt,
                                       __ATOMIC_RELAXED, __HIP_MEMORY_SCOPE_AGENT);
                int ok = 0;
                do {
                    unsigned f = __hip_atomic_load(flags + (size_t)tid * 32,
                                                   __ATOMIC_RELAXED, __HIP_MEMORY_SCOPE_AGENT);
                    ok = __syncthreads_and((int)(f >= tgt));
                    if (!ok) __builtin_amdgcn_s_sleep(2);
                } while (!ok);
                if (tid == 0)
                    __hip_atomic_store(go, tgt,
                                       __ATOMIC_RELAXED, __HIP_MEMORY_SCOPE_AGENT);
            } else {
                if (tid == 0) {
                    __hip_atomic_store(flags + (size_t)wg * 32, tgt,
                                       __ATOMIC_RELAXED, __HIP_MEMORY_SCOPE_AGENT);
                    while (__hip_atomic_load(go, __ATOMIC_RELAXED,
                                             __HIP_MEMORY_SCOPE_AGENT) < tgt)
                        __builtin_amdgcn_s_sleep(4);
                }
                __syncthreads();
            }
        }
    }
}

extern "C" void kernel_launch(void* const* d_in, const int* in_sizes, int n_in,
                              void* d_out, int out_size, void* d_ws, size_t ws_size,
                              hipStream_t stream) {
    const float* x     = (const float*)d_in[0];
    const float* w_ih0 = (const float*)d_in[1];
    const float* w_hh0 = (const float*)d_in[2];
    const float* b0    = (const float*)d_in[3];
    const float* w_ih1 = (const float*)d_in[4];
    const float* w_hh1 = (const float*)d_in[5];
    const float* b1    = (const float*)d_in[6];
    float* out = (float*)d_out;

    const size_t SZ_WARRH = 33554432;   // 4*256*16*1024*2
    const size_t SZ_WARRL = 16777216;   // 2*256*16*1024*2
    const size_t SZ_XT    = 33619968;   // 513*32*1024*2
    const size_t SZ_H     = 131072;     // 2*32*1024*2
    const size_t SZ_FLAGS = 33024;      // 256 lines x 128B + go line

    char* ws = (char*)d_ws;
    unsigned short* warrh = (unsigned short*)ws;
    unsigned short* warrl = (unsigned short*)(ws + SZ_WARRH);
    unsigned short* xTh   = (unsigned short*)(ws + SZ_WARRH + SZ_WARRL);
    unsigned short* xTl   = (unsigned short*)(ws + SZ_WARRH + SZ_WARRL + SZ_XT);
    char* zbase = ws + SZ_WARRH + SZ_WARRL + 2 * SZ_XT;
    unsigned short* h0h = (unsigned short*)zbase;
    unsigned short* h0l = (unsigned short*)(zbase + SZ_H);
    unsigned short* h1h = (unsigned short*)(zbase + 2 * SZ_H);
    unsigned short* h1l = (unsigned short*)(zbase + 3 * SZ_H);
    unsigned int* flags = (unsigned int*)(zbase + 4 * SZ_H);

    const size_t FULL = SZ_WARRH + SZ_WARRL + 2 * SZ_XT + 4 * SZ_H + SZ_FLAGS;
    const bool use_lo = ws_size >= FULL;

    hipMemsetAsync(zbase, 0, 4 * SZ_H + SZ_FLAGS, stream);   // h planes + flags, every launch (replay-safe)
    hipLaunchKernelGGL(k_xT,   dim3(16416), dim3(256), 0, stream, x, xTh, xTl, (int)use_lo);
    hipLaunchKernelGGL(k_warr, dim3(1024),  dim3(256), 0, stream,
                       w_ih0, w_hh0, w_ih1, w_hh1, warrh, warrl, (int)use_lo);
    if (use_lo) {
        hipLaunchKernelGGL(k_lstm<true>, dim3(256), dim3(256), 0, stream,
                           xTh, xTl, warrh, warrl, h0h, h0l, h1h, h1l, flags, b0, b1, out);
    } else {
        hipLaunchKernelGGL(k_lstm<false>, dim3(256), dim3(256), 0, stream,
                           xTh, xTl, warrh, warrl, h0h, h0l, h1h, h1l, flags, b0, b1, out);
    }
}